// Round 2
// baseline (360.008 us; speedup 1.0000x reference)
//
#include <hip/hip_runtime.h>

// ---- types / helpers -------------------------------------------------------
typedef __attribute__((ext_vector_type(8))) __bf16 bf16x8;   // 8 bf16 = 4 VGPRs
typedef __attribute__((ext_vector_type(4))) float  f32x4;
typedef unsigned short u16;

__device__ __forceinline__ u16 f2bf(float f) {
    union { float f; unsigned int i; } v; v.f = f;
    unsigned int r = v.i + 0x7fffu + ((v.i >> 16) & 1u);   // round-to-nearest-even
    return (u16)(r >> 16);
}
// pack two f32 -> two bf16 (lo=a, hi=b) in one v_perm
__device__ __forceinline__ unsigned pack2(float a, float b) {
    union { float f; unsigned u; } x, y; x.f = a; y.f = b;
    return __builtin_amdgcn_perm(y.u + 0x8000u, x.u + 0x8000u, 0x07060302u);
}

#define B_  64
#define S_  100
#define E_  512
#define H_  1024
#define VT_ 32000
#define Kc  128          // K-chunk in f32 elements
#define PITCH 128        // LDS row pitch in u16 (XOR-swizzled, no pad needed)
#define NS2 8            // K-slices for k2 (8 x 128 = 1024)
#define NS4 20           // K-slices for k4 (12 x 128 = 1536 Wih, 8 x 128 = 1024 Whh)

// ---- K1: encmean[b][e] = (1/S)*sum_s concat(emb_in[src], emb_pos[pos]) ----
__global__ __launch_bounds__(256, 1)
void k1_encmean(const int* __restrict__ src, const int* __restrict__ pos,
                const float* __restrict__ emb_in, const float* __restrict__ emb_pos,
                u16* __restrict__ encmean) {
    int b = blockIdx.x, q4 = blockIdx.y, t = threadIdx.x;
    __shared__ int sidx[S_], pidx[S_];
    __shared__ float part[256][4];
    if (t < S_) { sidx[t] = src[b * S_ + t]; pidx[t] = pos[b * S_ + t]; }
    __syncthreads();

    int f4 = t & 63, g = t >> 6;
    bool isPos = (q4 >= 2);
    const float* base = isPos ? emb_pos : emb_in;
    const int*   idx  = isPos ? pidx : sidx;
    int col = (q4 & 1) * 256 + f4 * 4;          // column within the 512-wide table

    float a0 = 0.f, a1 = 0.f, a2 = 0.f, a3 = 0.f;
    int s0 = g * 25;
    #pragma unroll 5
    for (int s = s0; s < s0 + 25; s++) {
        const float4 v = *(const float4*)(base + (size_t)idx[s] * E_ + col);
        a0 += v.x; a1 += v.y; a2 += v.z; a3 += v.w;
    }
    part[t][0] = a0; part[t][1] = a1; part[t][2] = a2; part[t][3] = a3;
    __syncthreads();

    if (t < 64) {
        const float inv = 1.0f / (float)S_;
        float r0 = 0.f, r1 = 0.f, r2 = 0.f, r3 = 0.f;
        #pragma unroll
        for (int g2 = 0; g2 < 4; g2++) {
            r0 += part[g2 * 64 + t][0]; r1 += part[g2 * 64 + t][1];
            r2 += part[g2 * 64 + t][2]; r3 += part[g2 * 64 + t][3];
        }
        int e = q4 * 256 + t * 4;
        u16* o = encmean + (size_t)b * (2 * E_) + e;
        o[0] = f2bf(r0 * inv); o[1] = f2bf(r1 * inv);
        o[2] = f2bf(r2 * inv); o[3] = f2bf(r3 * inv);
    }
}

// ---- LDS-staged double-buffered MFMA GEMM over a K-slice -------------------
// acc += A[64 rows, LDA][koff..koff+KLEN] * W[64 rows jt.., LDW][koff..]^T
// LDS layout: row rr (0..63), 16B-unit U (0..15) stored at U ^ (rr & 15).
// NC==1 degenerates to stage + sync + MFMA (single buffer, one latency round).
#define MFMA16(a, bfrag, c) __builtin_amdgcn_mfma_f32_16x16x32_bf16((a), (bfrag), (c), 0, 0, 0)

template<int KLEN, int LDA, int LDW>
__device__ __forceinline__ void gemm_lds(const u16* __restrict__ A,
                                         const float* __restrict__ W,
                                         int jt, int koff, u16* __restrict__ ldsW,
                                         f32x4 acc[4], int t) {
    constexpr int NC = KLEN / Kc;
    const int lane = t & 63, w = t >> 6, m = lane & 15, q = lane >> 4;
    const int r = t >> 2, c4 = t & 3;          // staging: 4 threads per W row
    const float* wsrc = W + (size_t)(jt + r) * LDW + koff + c4 * 4;
    const u16*   arow = A + (size_t)(w * 16 + m) * LDA + koff + q * 8;
    const int halfoff = (c4 & 1) * 4;          // u16 offset within 16B unit

    float4 v[8];
    // ---- prologue: stage chunk 0 into buf 0 ----
    #pragma unroll
    for (int i = 0; i < 8; i++) v[i] = *(const float4*)(wsrc + i * 16);
    #pragma unroll
    for (int i = 0; i < 8; i++) {
        int U = (c4 >> 1) + 2 * i;
        uint2 p; p.x = pack2(v[i].x, v[i].y); p.y = pack2(v[i].z, v[i].w);
        *(uint2*)(ldsW + r * PITCH + ((U ^ (r & 15)) * 8) + halfoff) = p;
    }
    __syncthreads();

    for (int c = 0; c < NC; c++) {
        // issue next chunk's global loads (land while we MFMA)
        if (c + 1 < NC) {
            #pragma unroll
            for (int i = 0; i < 8; i++)
                v[i] = *(const float4*)(wsrc + (c + 1) * Kc + i * 16);
        }
        // compute on buf c&1
        const u16* lb = ldsW + (c & 1) * (64 * PITCH);
        const u16* ar = arow + c * Kc;
        #pragma unroll
        for (int ks = 0; ks < 4; ks++) {
            bf16x8 a = *(const bf16x8*)(ar + ks * 32);
            #pragma unroll
            for (int f = 0; f < 4; f++) {
                int rr = f * 16 + m;
                int U  = ks * 4 + q;
                bf16x8 bfr = *(const bf16x8*)(lb + rr * PITCH + ((U ^ (rr & 15)) * 8));
                acc[f] = MFMA16(a, bfr, acc[f]);
            }
        }
        // write the staged chunk
        if (c + 1 < NC) {
            u16* wd = ldsW + ((c + 1) & 1) * (64 * PITCH) + r * PITCH;
            #pragma unroll
            for (int i = 0; i < 8; i++) {
                int U = (c4 >> 1) + 2 * i;
                uint2 p; p.x = pack2(v[i].x, v[i].y); p.y = pack2(v[i].z, v[i].w);
                *(uint2*)(wd + ((U ^ (r & 15)) * 8) + halfoff) = p;
            }
        }
        __syncthreads();
    }
}

// ---- K2p: part2[sp][b][j] = encmean[b][sp*128..+128] @ Wscale^T slice -----
// grid (16, 8): 128 blocks, NC=1 -> single stage latency per block.
__global__ __launch_bounds__(256, 2)
void k2_h0p(const u16* __restrict__ encmean, const float* __restrict__ Wscale,
            float* __restrict__ part2) {
    __shared__ u16 ldsW[64 * PITCH];
    int t = threadIdx.x, lane = t & 63, w = t >> 6, m = lane & 15, q = lane >> 4;
    int jt = blockIdx.x * 64, sp = blockIdx.y;
    f32x4 acc[4] = {{0,0,0,0},{0,0,0,0},{0,0,0,0},{0,0,0,0}};
    gemm_lds<Kc, 2 * E_, 2 * E_>(encmean, Wscale, jt, sp * Kc, ldsW, acc, t);
    #pragma unroll
    for (int f = 0; f < 4; f++) {
        int j = jt + 16 * f + m;
        #pragma unroll
        for (int r2 = 0; r2 < 4; r2++) {
            int bb = w * 16 + q * 4 + r2;
            part2[(size_t)(sp * B_ + bb) * H_ + j] = acc[f][r2];
        }
    }
}

// ---- K3: h0 = sum(part2)+bias; energy -> softmax -> context; x; h0b ------
// Also zeroes the k4 slice-completion counters (runs strictly before k4p).
__global__ __launch_bounds__(256, 1)
void k3_attn(const int* __restrict__ src, const int* __restrict__ pos,
             const int* __restrict__ tgt,
             const float* __restrict__ emb_in, const float* __restrict__ emb_pos,
             const float* __restrict__ emb_out,
             const float* __restrict__ part2, const float* __restrict__ bscale,
             u16* __restrict__ x, u16* __restrict__ h0b,
             unsigned* __restrict__ cnt4) {
    int b = blockIdx.x, t = threadIdx.x;       // 256 threads
    __shared__ float h0s[2 * E_];
    __shared__ int sidx[S_], pidx[S_];
    __shared__ float energy[S_];
    __shared__ float align_s[S_];

    if (b == 0 && t < 16) cnt4[t] = 0;         // reset k4's jt counters

    for (int i = t; i < 2 * E_; i += 256) {    // reduce K-split partials + bias
        float v = bscale[i];
        #pragma unroll
        for (int ks = 0; ks < NS2; ks++) v += part2[(size_t)(ks * B_ + b) * H_ + i];
        h0s[i] = v;
        h0b[(size_t)b * H_ + i] = f2bf(v);     // bf16 copy for K4's Whh GEMM
    }
    if (t < S_) { sidx[t] = src[b * S_ + t]; pidx[t] = pos[b * S_ + t]; }
    __syncthreads();

    int lane = t & 63, w = t >> 6;
    for (int s = w; s < S_; s += 4) {
        const float* ri = emb_in  + (size_t)sidx[s] * E_;
        const float* rp = emb_pos + (size_t)pidx[s] * E_;
        float acc = 0.f;
        #pragma unroll
        for (int ii = 0; ii < 8; ii++) { int k = lane + 64 * ii; acc += ri[k] * h0s[k]; }
        #pragma unroll
        for (int ii = 0; ii < 8; ii++) { int k = lane + 64 * ii; acc += rp[k] * h0s[E_ + k]; }
        #pragma unroll
        for (int off = 32; off; off >>= 1) acc += __shfl_down(acc, off);
        if (lane == 0) energy[s] = acc;
    }
    __syncthreads();

    if (t < 64) {
        float e0 = energy[t];
        float e1 = (t + 64 < S_) ? energy[t + 64] : -1e30f;
        float mx = fmaxf(e0, e1);
        #pragma unroll
        for (int off = 32; off; off >>= 1) mx = fmaxf(mx, __shfl_xor(mx, off));
        float p0 = expf(e0 - mx);
        float p1 = (t + 64 < S_) ? expf(e1 - mx) : 0.f;
        float ss = p0 + p1;
        #pragma unroll
        for (int off = 32; off; off >>= 1) ss += __shfl_xor(ss, off);
        float inv = 1.0f / (ss * (float)S_);   // fold torch.mean's 1/S here
        align_s[t] = p0 * inv;
        if (t + 64 < S_) align_s[t + 64] = p1 * inv;
    }
    __syncthreads();

    if (t < 128) {
        int o = t;
        bool isPos = (o >= 64);
        const float* base = isPos ? emb_pos : emb_in;
        const int* idx  = isPos ? pidx : sidx;
        int eo = (o & 63) * 8;
        float c[8] = {0,0,0,0,0,0,0,0};
        for (int s = 0; s < S_; s++) {
            const float* row = base + (size_t)idx[s] * E_ + eo;
            float al = align_s[s];
            const float4 v0 = *(const float4*)(row);
            const float4 v1 = *(const float4*)(row + 4);
            c[0] += al * v0.x; c[1] += al * v0.y; c[2] += al * v0.z; c[3] += al * v0.w;
            c[4] += al * v1.x; c[5] += al * v1.y; c[6] += al * v1.z; c[7] += al * v1.w;
        }
        u16* xo = x + (size_t)b * (E_ + H_) + E_ + o * 8;
        #pragma unroll
        for (int i = 0; i < 8; i++) xo[i] = f2bf(c[i]);
    } else {
        int i = t - 128;                        // 128 threads x 4 elems = 512
        int tw = tgt[b];
        const float4 v = *((const float4*)(emb_out + (size_t)tw * E_) + i);
        ushort4 o; o.x = f2bf(v.x); o.y = f2bf(v.y); o.z = f2bf(v.z); o.w = f2bf(v.w);
        *((ushort4*)(x + (size_t)b * (E_ + H_)) + i) = o;
    }
}

// ---- K4p: partial z slices + fused last-block reduction -------------------
// grid (16, 20): sp<12 -> x@Wih slice; sp>=12 -> h0@Whh slice. NC=1.
// Last block per jt (device-atomic count) reduces 20 partials + bias + tanh.
__global__ __launch_bounds__(256, 2)
void k4_hp(const u16* __restrict__ xb, const float* __restrict__ Wih,
           const u16* __restrict__ h0b, const float* __restrict__ Whh,
           const float* __restrict__ bih, const float* __restrict__ bhh,
           float* __restrict__ part4, unsigned* __restrict__ cnt4,
           float* __restrict__ houtf, u16* __restrict__ hbf) {
    __shared__ u16 ldsW[64 * PITCH];
    __shared__ int lastflag;
    int t = threadIdx.x, lane = t & 63, w = t >> 6, m = lane & 15, q = lane >> 4;
    int jt = blockIdx.x * 64, sp = blockIdx.y;
    f32x4 acc[4] = {{0,0,0,0},{0,0,0,0},{0,0,0,0},{0,0,0,0}};
    if (sp < 12) gemm_lds<Kc, E_ + H_, E_ + H_>(xb,  Wih, jt, sp * Kc,        ldsW, acc, t);
    else         gemm_lds<Kc, H_,      H_     >(h0b, Whh, jt, (sp - 12) * Kc, ldsW, acc, t);
    #pragma unroll
    for (int f = 0; f < 4; f++) {
        int j = jt + 16 * f + m;
        #pragma unroll
        for (int r2 = 0; r2 < 4; r2++) {
            int bb = w * 16 + q * 4 + r2;
            part4[(size_t)(sp * B_ + bb) * H_ + j] = acc[f][r2];
        }
    }
    __threadfence();                            // release: each thread's stores
    __syncthreads();
    if (t == 0) lastflag = (atomicAdd(&cnt4[blockIdx.x], 1u) == NS4 - 1);
    __syncthreads();
    if (lastflag) {
        __threadfence();                        // acquire: see peers' partials
        int jj = jt + (t & 15) * 4;             // 16 j-quads cover this jt's 64 j
        int b0 = (t >> 4) * 4;                  // 16 groups x 4 b = 64 b
        for (int bb = b0; bb < b0 + 4; bb++) {
            float4 s  = *(const float4*)(bih + jj);
            const float4 b2 = *(const float4*)(bhh + jj);
            s.x += b2.x; s.y += b2.y; s.z += b2.z; s.w += b2.w;
            #pragma unroll
            for (int ks = 0; ks < NS4; ks++) {
                const float4 p = *(const float4*)(part4 + (size_t)(ks * B_ + bb) * H_ + jj);
                s.x += p.x; s.y += p.y; s.z += p.z; s.w += p.w;
            }
            float4 h; h.x = tanhf(s.x); h.y = tanhf(s.y); h.z = tanhf(s.z); h.w = tanhf(s.w);
            *(float4*)(houtf + (size_t)bb * H_ + jj) = h;
            ushort4 o; o.x = f2bf(h.x); o.y = f2bf(h.y); o.z = f2bf(h.z); o.w = f2bf(h.w);
            *(ushort4*)(hbf + (size_t)bb * H_ + jj) = o;
        }
    }
}

// ---- K5: out = h @ W_proj^T + b_proj  (131 MB f32 weights, HBM-bound) -----
__global__ __launch_bounds__(256, 2)
void k5_out(const u16* __restrict__ hb, const float* __restrict__ Wp,
            const float* __restrict__ bp, float* __restrict__ out) {
    __shared__ u16 ldsW[2 * 64 * PITCH];
    int t = threadIdx.x, lane = t & 63, w = t >> 6, m = lane & 15, q = lane >> 4;
    int jt = blockIdx.x * 64;
    f32x4 acc[4] = {{0,0,0,0},{0,0,0,0},{0,0,0,0},{0,0,0,0}};
    gemm_lds<H_, H_, H_>(hb, Wp, jt, 0, ldsW, acc, t);
    #pragma unroll
    for (int f = 0; f < 4; f++) {
        int j = jt + 16 * f + m;
        float bias = bp[j];
        #pragma unroll
        for (int r = 0; r < 4; r++) {
            int b = w * 16 + q * 4 + r;
            out[(size_t)b * VT_ + j] = acc[f][r] + bias;
        }
    }
}

// ---- launch ---------------------------------------------------------------
extern "C" void kernel_launch(void* const* d_in, const int* in_sizes, int n_in,
                              void* d_out, int out_size, void* d_ws, size_t ws_size,
                              hipStream_t stream) {
    const int*   src     = (const int*)d_in[0];
    const int*   pos     = (const int*)d_in[1];
    const int*   tgt     = (const int*)d_in[2];
    const float* emb_in  = (const float*)d_in[5];
    const float* emb_out = (const float*)d_in[6];
    const float* emb_pos = (const float*)d_in[7];
    const float* Wscale  = (const float*)d_in[8];
    const float* bscale  = (const float*)d_in[9];
    const float* Wih     = (const float*)d_in[10];
    const float* bih     = (const float*)d_in[11];
    const float* Whh     = (const float*)d_in[12];
    const float* bhh     = (const float*)d_in[13];
    const float* Wproj   = (const float*)d_in[14];
    const float* bproj   = (const float*)d_in[15];

    char* ws = (char*)d_ws;
    u16*      encmean = (u16*)(ws);               // 64*1024*2      = 131072 B
    u16*      xb      = (u16*)(ws + 131072);      // 64*1536*2      = 196608 B
    u16*      h0b     = (u16*)(ws + 327680);      // 64*1024*2      = 131072 B
    u16*      hbf     = (u16*)(ws + 458752);      // 64*1024*2      = 131072 B
    unsigned* cnt4    = (unsigned*)(ws + 589824); // 16*4 (pad to 1024)
    float*    part2   = (float*)(ws + 590848);    // 8*64*1024*4    = 2097152 B
    float*    part4   = (float*)(ws + 2688000);   // 20*64*1024*4   = 5242880 B
                                                  // total ~7.93 MB

    float* out   = (float*)d_out;                 // [64][32000] f32
    float* houtf = out + (size_t)B_ * VT_;        // [64][1024]  f32 (Output 1)

    hipLaunchKernelGGL(k1_encmean, dim3(B_, 4),        dim3(256), 0, stream,
                       src, pos, emb_in, emb_pos, encmean);
    hipLaunchKernelGGL(k2_h0p,     dim3(H_ / 64, NS2), dim3(256), 0, stream,
                       encmean, Wscale, part2);
    hipLaunchKernelGGL(k3_attn,    dim3(B_),           dim3(256), 0, stream,
                       src, pos, tgt, emb_in, emb_pos, emb_out, part2, bscale,
                       xb, h0b, cnt4);
    hipLaunchKernelGGL(k4_hp,      dim3(H_ / 64, NS4), dim3(256), 0, stream,
                       xb, Wih, h0b, Whh, bih, bhh, part4, cnt4, houtf, hbf);
    hipLaunchKernelGGL(k5_out,     dim3(VT_ / 64),     dim3(256), 0, stream,
                       hbf, Wproj, bproj, out);
}

// Round 3
// 329.439 us; speedup vs baseline: 1.0928x; 1.0928x over previous
//
#include <hip/hip_runtime.h>

// ---- types / helpers -------------------------------------------------------
typedef __attribute__((ext_vector_type(8))) __bf16 bf16x8;   // 8 bf16 = 4 VGPRs
typedef __attribute__((ext_vector_type(4))) float  f32x4;
typedef unsigned short u16;

__device__ __forceinline__ u16 f2bf(float f) {
    union { float f; unsigned int i; } v; v.f = f;
    unsigned int r = v.i + 0x7fffu + ((v.i >> 16) & 1u);   // round-to-nearest-even
    return (u16)(r >> 16);
}
// pack two f32 -> two bf16 (lo=a, hi=b) in one v_perm
__device__ __forceinline__ unsigned pack2(float a, float b) {
    union { float f; unsigned u; } x, y; x.f = a; y.f = b;
    return __builtin_amdgcn_perm(y.u + 0x8000u, x.u + 0x8000u, 0x07060302u);
}

#define B_  64
#define S_  100
#define E_  512
#define H_  1024
#define VT_ 32000
#define Kc  128          // K-chunk in f32 elements
#define PITCH 128        // LDS row pitch in u16 (XOR-swizzled, no pad needed)
#define NS2 8            // K-slices for k2 (8 x 128 = 1024)
#define NS4 20           // K-slices for k4 (12 x 128 = 1536 Wih, 8 x 128 = 1024 Whh)

// NOTE (journal): R2's fused last-block reduction with per-block
// __threadfence() cost ~+40us (320 device-scope fences -> per-XCD L2
// writebacks). Inter-kernel boundaries are the cheap coherence mechanism;
// keep the reduce as its own kernel.

// ---- K1: encmean[b][e] = (1/S)*sum_s concat(emb_in[src], emb_pos[pos]) ----
__global__ __launch_bounds__(256, 1)
void k1_encmean(const int* __restrict__ src, const int* __restrict__ pos,
                const float* __restrict__ emb_in, const float* __restrict__ emb_pos,
                u16* __restrict__ encmean) {
    int b = blockIdx.x, q4 = blockIdx.y, t = threadIdx.x;
    __shared__ int sidx[S_], pidx[S_];
    __shared__ float part[256][4];
    if (t < S_) { sidx[t] = src[b * S_ + t]; pidx[t] = pos[b * S_ + t]; }
    __syncthreads();

    int f4 = t & 63, g = t >> 6;
    bool isPos = (q4 >= 2);
    const float* base = isPos ? emb_pos : emb_in;
    const int*   idx  = isPos ? pidx : sidx;
    int col = (q4 & 1) * 256 + f4 * 4;          // column within the 512-wide table

    float a0 = 0.f, a1 = 0.f, a2 = 0.f, a3 = 0.f;
    int s0 = g * 25;
    #pragma unroll 5
    for (int s = s0; s < s0 + 25; s++) {
        const float4 v = *(const float4*)(base + (size_t)idx[s] * E_ + col);
        a0 += v.x; a1 += v.y; a2 += v.z; a3 += v.w;
    }
    part[t][0] = a0; part[t][1] = a1; part[t][2] = a2; part[t][3] = a3;
    __syncthreads();

    if (t < 64) {
        const float inv = 1.0f / (float)S_;
        float r0 = 0.f, r1 = 0.f, r2 = 0.f, r3 = 0.f;
        #pragma unroll
        for (int g2 = 0; g2 < 4; g2++) {
            r0 += part[g2 * 64 + t][0]; r1 += part[g2 * 64 + t][1];
            r2 += part[g2 * 64 + t][2]; r3 += part[g2 * 64 + t][3];
        }
        int e = q4 * 256 + t * 4;
        u16* o = encmean + (size_t)b * (2 * E_) + e;
        o[0] = f2bf(r0 * inv); o[1] = f2bf(r1 * inv);
        o[2] = f2bf(r2 * inv); o[3] = f2bf(r3 * inv);
    }
}

// ---- LDS-staged double-buffered MFMA GEMM over a K-slice -------------------
// acc += A[64 rows, LDA][koff..koff+KLEN] * W[64 rows jt.., LDW][koff..]^T
// LDS layout: row rr (0..63), 16B-unit U (0..15) stored at U ^ (rr & 15).
// NC==1 degenerates to stage + sync + MFMA (single buffer, one latency round).
#define MFMA16(a, bfrag, c) __builtin_amdgcn_mfma_f32_16x16x32_bf16((a), (bfrag), (c), 0, 0, 0)

template<int KLEN, int LDA, int LDW>
__device__ __forceinline__ void gemm_lds(const u16* __restrict__ A,
                                         const float* __restrict__ W,
                                         int jt, int koff, u16* __restrict__ ldsW,
                                         f32x4 acc[4], int t) {
    constexpr int NC = KLEN / Kc;
    const int lane = t & 63, w = t >> 6, m = lane & 15, q = lane >> 4;
    const int r = t >> 2, c4 = t & 3;          // staging: 4 threads per W row
    const float* wsrc = W + (size_t)(jt + r) * LDW + koff + c4 * 4;
    const u16*   arow = A + (size_t)(w * 16 + m) * LDA + koff + q * 8;
    const int halfoff = (c4 & 1) * 4;          // u16 offset within 16B unit

    float4 v[8];
    // ---- prologue: stage chunk 0 into buf 0 ----
    #pragma unroll
    for (int i = 0; i < 8; i++) v[i] = *(const float4*)(wsrc + i * 16);
    #pragma unroll
    for (int i = 0; i < 8; i++) {
        int U = (c4 >> 1) + 2 * i;
        uint2 p; p.x = pack2(v[i].x, v[i].y); p.y = pack2(v[i].z, v[i].w);
        *(uint2*)(ldsW + r * PITCH + ((U ^ (r & 15)) * 8) + halfoff) = p;
    }
    __syncthreads();

    for (int c = 0; c < NC; c++) {
        // issue next chunk's global loads (land while we MFMA)
        if (c + 1 < NC) {
            #pragma unroll
            for (int i = 0; i < 8; i++)
                v[i] = *(const float4*)(wsrc + (c + 1) * Kc + i * 16);
        }
        // compute on buf c&1
        const u16* lb = ldsW + (c & 1) * (64 * PITCH);
        const u16* ar = arow + c * Kc;
        #pragma unroll
        for (int ks = 0; ks < 4; ks++) {
            bf16x8 a = *(const bf16x8*)(ar + ks * 32);
            #pragma unroll
            for (int f = 0; f < 4; f++) {
                int rr = f * 16 + m;
                int U  = ks * 4 + q;
                bf16x8 bfr = *(const bf16x8*)(lb + rr * PITCH + ((U ^ (rr & 15)) * 8));
                acc[f] = MFMA16(a, bfr, acc[f]);
            }
        }
        // write the staged chunk
        if (c + 1 < NC) {
            u16* wd = ldsW + ((c + 1) & 1) * (64 * PITCH) + r * PITCH;
            #pragma unroll
            for (int i = 0; i < 8; i++) {
                int U = (c4 >> 1) + 2 * i;
                uint2 p; p.x = pack2(v[i].x, v[i].y); p.y = pack2(v[i].z, v[i].w);
                *(uint2*)(wd + ((U ^ (r & 15)) * 8) + halfoff) = p;
            }
        }
        __syncthreads();
    }
}

// ---- K2p: part2[sp][b][j] = encmean[b][sp*128..+128] @ Wscale^T slice -----
// grid (16, 8): 128 blocks, NC=1 -> single stage latency per block.
__global__ __launch_bounds__(256, 2)
void k2_h0p(const u16* __restrict__ encmean, const float* __restrict__ Wscale,
            float* __restrict__ part2) {
    __shared__ u16 ldsW[64 * PITCH];
    int t = threadIdx.x, lane = t & 63, w = t >> 6, m = lane & 15, q = lane >> 4;
    int jt = blockIdx.x * 64, sp = blockIdx.y;
    f32x4 acc[4] = {{0,0,0,0},{0,0,0,0},{0,0,0,0},{0,0,0,0}};
    gemm_lds<Kc, 2 * E_, 2 * E_>(encmean, Wscale, jt, sp * Kc, ldsW, acc, t);
    #pragma unroll
    for (int f = 0; f < 4; f++) {
        int j = jt + 16 * f + m;
        #pragma unroll
        for (int r2 = 0; r2 < 4; r2++) {
            int bb = w * 16 + q * 4 + r2;
            part2[(size_t)(sp * B_ + bb) * H_ + j] = acc[f][r2];
        }
    }
}

// ---- K3: h0 = sum(part2)+bias; energy -> softmax -> context; x; h0b ------
__global__ __launch_bounds__(256, 1)
void k3_attn(const int* __restrict__ src, const int* __restrict__ pos,
             const int* __restrict__ tgt,
             const float* __restrict__ emb_in, const float* __restrict__ emb_pos,
             const float* __restrict__ emb_out,
             const float* __restrict__ part2, const float* __restrict__ bscale,
             u16* __restrict__ x, u16* __restrict__ h0b) {
    int b = blockIdx.x, t = threadIdx.x;       // 256 threads
    __shared__ float h0s[2 * E_];
    __shared__ int sidx[S_], pidx[S_];
    __shared__ float energy[S_];
    __shared__ float align_s[S_];

    for (int i = t; i < 2 * E_; i += 256) {    // reduce K-split partials + bias
        float v = bscale[i];
        #pragma unroll
        for (int ks = 0; ks < NS2; ks++) v += part2[(size_t)(ks * B_ + b) * H_ + i];
        h0s[i] = v;
        h0b[(size_t)b * H_ + i] = f2bf(v);     // bf16 copy for K4's Whh GEMM
    }
    if (t < S_) { sidx[t] = src[b * S_ + t]; pidx[t] = pos[b * S_ + t]; }
    __syncthreads();

    int lane = t & 63, w = t >> 6;
    for (int s = w; s < S_; s += 4) {
        const float* ri = emb_in  + (size_t)sidx[s] * E_;
        const float* rp = emb_pos + (size_t)pidx[s] * E_;
        float acc = 0.f;
        #pragma unroll
        for (int ii = 0; ii < 8; ii++) { int k = lane + 64 * ii; acc += ri[k] * h0s[k]; }
        #pragma unroll
        for (int ii = 0; ii < 8; ii++) { int k = lane + 64 * ii; acc += rp[k] * h0s[E_ + k]; }
        #pragma unroll
        for (int off = 32; off; off >>= 1) acc += __shfl_down(acc, off);
        if (lane == 0) energy[s] = acc;
    }
    __syncthreads();

    if (t < 64) {
        float e0 = energy[t];
        float e1 = (t + 64 < S_) ? energy[t + 64] : -1e30f;
        float mx = fmaxf(e0, e1);
        #pragma unroll
        for (int off = 32; off; off >>= 1) mx = fmaxf(mx, __shfl_xor(mx, off));
        float p0 = expf(e0 - mx);
        float p1 = (t + 64 < S_) ? expf(e1 - mx) : 0.f;
        float ss = p0 + p1;
        #pragma unroll
        for (int off = 32; off; off >>= 1) ss += __shfl_xor(ss, off);
        float inv = 1.0f / (ss * (float)S_);   // fold torch.mean's 1/S here
        align_s[t] = p0 * inv;
        if (t + 64 < S_) align_s[t + 64] = p1 * inv;
    }
    __syncthreads();

    if (t < 128) {
        int o = t;
        bool isPos = (o >= 64);
        const float* base = isPos ? emb_pos : emb_in;
        const int* idx  = isPos ? pidx : sidx;
        int eo = (o & 63) * 8;
        float c[8] = {0,0,0,0,0,0,0,0};
        for (int s = 0; s < S_; s++) {
            const float* row = base + (size_t)idx[s] * E_ + eo;
            float al = align_s[s];
            const float4 v0 = *(const float4*)(row);
            const float4 v1 = *(const float4*)(row + 4);
            c[0] += al * v0.x; c[1] += al * v0.y; c[2] += al * v0.z; c[3] += al * v0.w;
            c[4] += al * v1.x; c[5] += al * v1.y; c[6] += al * v1.z; c[7] += al * v1.w;
        }
        u16* xo = x + (size_t)b * (E_ + H_) + E_ + o * 8;
        #pragma unroll
        for (int i = 0; i < 8; i++) xo[i] = f2bf(c[i]);
    } else {
        int i = t - 128;                        // 128 threads x 4 elems = 512
        int tw = tgt[b];
        const float4 v = *((const float4*)(emb_out + (size_t)tw * E_) + i);
        ushort4 o; o.x = f2bf(v.x); o.y = f2bf(v.y); o.z = f2bf(v.z); o.w = f2bf(v.w);
        *((ushort4*)(x + (size_t)b * (E_ + H_)) + i) = o;
    }
}

// ---- K4p: partial z slices. grid (16, 20): sp<12 -> x@Wih; sp>=12 -> h0@Whh
__global__ __launch_bounds__(256, 2)
void k4_hp(const u16* __restrict__ xb, const float* __restrict__ Wih,
           const u16* __restrict__ h0b, const float* __restrict__ Whh,
           float* __restrict__ part4) {
    __shared__ u16 ldsW[64 * PITCH];
    int t = threadIdx.x, lane = t & 63, w = t >> 6, m = lane & 15, q = lane >> 4;
    int jt = blockIdx.x * 64, sp = blockIdx.y;
    f32x4 acc[4] = {{0,0,0,0},{0,0,0,0},{0,0,0,0},{0,0,0,0}};
    if (sp < 12) gemm_lds<Kc, E_ + H_, E_ + H_>(xb,  Wih, jt, sp * Kc,        ldsW, acc, t);
    else         gemm_lds<Kc, H_,      H_     >(h0b, Whh, jt, (sp - 12) * Kc, ldsW, acc, t);
    #pragma unroll
    for (int f = 0; f < 4; f++) {
        int j = jt + 16 * f + m;
        #pragma unroll
        for (int r2 = 0; r2 < 4; r2++) {
            int bb = w * 16 + q * 4 + r2;
            part4[(size_t)(sp * B_ + bb) * H_ + j] = acc[f][r2];
        }
    }
}

// ---- K4r: h = tanh(sum(part4) + bih + bhh); f32 out + bf16 copy -----------
__global__ __launch_bounds__(256, 1)
void k4_red(const float* __restrict__ part4,
            const float* __restrict__ bih, const float* __restrict__ bhh,
            float* __restrict__ houtf, u16* __restrict__ hbf) {
    int b = blockIdx.x, t = threadIdx.x;
    int j = t * 4;
    float4 s  = *(const float4*)(bih + j);
    const float4 b2 = *(const float4*)(bhh + j);
    s.x += b2.x; s.y += b2.y; s.z += b2.z; s.w += b2.w;
    #pragma unroll
    for (int ks = 0; ks < NS4; ks++) {
        const float4 p = *(const float4*)(part4 + (size_t)(ks * B_ + b) * H_ + j);
        s.x += p.x; s.y += p.y; s.z += p.z; s.w += p.w;
    }
    float4 h; h.x = tanhf(s.x); h.y = tanhf(s.y); h.z = tanhf(s.z); h.w = tanhf(s.w);
    *(float4*)(houtf + (size_t)b * H_ + j) = h;
    ushort4 o; o.x = f2bf(h.x); o.y = f2bf(h.y); o.z = f2bf(h.z); o.w = f2bf(h.w);
    *(ushort4*)(hbf + (size_t)b * H_ + j) = o;
}

// ---- K5: out = h @ W_proj^T + b_proj  (131 MB f32 weights, HBM-bound) -----
__global__ __launch_bounds__(256, 2)
void k5_out(const u16* __restrict__ hb, const float* __restrict__ Wp,
            const float* __restrict__ bp, float* __restrict__ out) {
    __shared__ u16 ldsW[2 * 64 * PITCH];
    int t = threadIdx.x, lane = t & 63, w = t >> 6, m = lane & 15, q = lane >> 4;
    int jt = blockIdx.x * 64;
    f32x4 acc[4] = {{0,0,0,0},{0,0,0,0},{0,0,0,0},{0,0,0,0}};
    gemm_lds<H_, H_, H_>(hb, Wp, jt, 0, ldsW, acc, t);
    #pragma unroll
    for (int f = 0; f < 4; f++) {
        int j = jt + 16 * f + m;
        float bias = bp[j];
        #pragma unroll
        for (int r = 0; r < 4; r++) {
            int b = w * 16 + q * 4 + r;
            out[(size_t)b * VT_ + j] = acc[f][r] + bias;
        }
    }
}

// ---- launch ---------------------------------------------------------------
extern "C" void kernel_launch(void* const* d_in, const int* in_sizes, int n_in,
                              void* d_out, int out_size, void* d_ws, size_t ws_size,
                              hipStream_t stream) {
    const int*   src     = (const int*)d_in[0];
    const int*   pos     = (const int*)d_in[1];
    const int*   tgt     = (const int*)d_in[2];
    const float* emb_in  = (const float*)d_in[5];
    const float* emb_out = (const float*)d_in[6];
    const float* emb_pos = (const float*)d_in[7];
    const float* Wscale  = (const float*)d_in[8];
    const float* bscale  = (const float*)d_in[9];
    const float* Wih     = (const float*)d_in[10];
    const float* bih     = (const float*)d_in[11];
    const float* Whh     = (const float*)d_in[12];
    const float* bhh     = (const float*)d_in[13];
    const float* Wproj   = (const float*)d_in[14];
    const float* bproj   = (const float*)d_in[15];

    char* ws = (char*)d_ws;
    u16*   encmean = (u16*)(ws);                 // 64*1024*2      = 131072 B
    u16*   xb      = (u16*)(ws + 131072);        // 64*1536*2      = 196608 B
    u16*   h0b     = (u16*)(ws + 327680);        // 64*1024*2      = 131072 B
    u16*   hbf     = (u16*)(ws + 458752);        // 64*1024*2      = 131072 B
    float* part2   = (float*)(ws + 589824);      // 8*64*1024*4    = 2097152 B
    float* part4   = (float*)(ws + 2686976);     // 20*64*1024*4   = 5242880 B
                                                 // total ~7.93 MB

    float* out   = (float*)d_out;                 // [64][32000] f32
    float* houtf = out + (size_t)B_ * VT_;        // [64][1024]  f32 (Output 1)

    hipLaunchKernelGGL(k1_encmean, dim3(B_, 4),        dim3(256), 0, stream,
                       src, pos, emb_in, emb_pos, encmean);
    hipLaunchKernelGGL(k2_h0p,     dim3(H_ / 64, NS2), dim3(256), 0, stream,
                       encmean, Wscale, part2);
    hipLaunchKernelGGL(k3_attn,    dim3(B_),           dim3(256), 0, stream,
                       src, pos, tgt, emb_in, emb_pos, emb_out, part2, bscale,
                       xb, h0b);
    hipLaunchKernelGGL(k4_hp,      dim3(H_ / 64, NS4), dim3(256), 0, stream,
                       xb, Wih, h0b, Whh, part4);
    hipLaunchKernelGGL(k4_red,     dim3(B_),           dim3(256), 0, stream,
                       part4, bih, bhh, houtf, hbf);
    hipLaunchKernelGGL(k5_out,     dim3(VT_ / 64),     dim3(256), 0, stream,
                       hbf, Wproj, bproj, out);
}

// Round 4
// 319.564 us; speedup vs baseline: 1.1266x; 1.0309x over previous
//
#include <hip/hip_runtime.h>

// ---- types / helpers -------------------------------------------------------
typedef __attribute__((ext_vector_type(8))) __bf16 bf16x8;   // 8 bf16 = 4 VGPRs
typedef __attribute__((ext_vector_type(4))) float  f32x4;
typedef unsigned short u16;

__device__ __forceinline__ u16 f2bf(float f) {
    union { float f; unsigned int i; } v; v.f = f;
    unsigned int r = v.i + 0x7fffu + ((v.i >> 16) & 1u);   // round-to-nearest-even
    return (u16)(r >> 16);
}
// pack two f32 -> two bf16 (lo=a, hi=b) in one v_perm
__device__ __forceinline__ unsigned pack2(float a, float b) {
    union { float f; unsigned u; } x, y; x.f = a; y.f = b;
    return __builtin_amdgcn_perm(y.u + 0x8000u, x.u + 0x8000u, 0x07060302u);
}

#define B_  64
#define S_  100
#define E_  512
#define H_  1024
#define VT_ 32000
#define Kc  128          // K-chunk in f32 elements
#define PITCH 128        // LDS row pitch in u16 (XOR-swizzled, no pad needed)
#define NS2 4            // K-slices for k2 (4 x 256 = 1024)  [R1-proven]
#define NS4 10           // K-slices for k4 (6 x 256 Wih, 4 x 256 Whh)  [R1-proven]

// JOURNAL:
//  R1 (this structure): 322.0us.  R2 fused last-block reduce w/ per-block
//  __threadfence(): +38us (320 device fences -> per-XCD L2 writebacks).
//  R3 NC=1 slices (NS2=8/NS4=20): +7us vs R1 (2x partial traffic + 2x block
//  prologues; critical path per block unchanged since dbuf already hides
//  the inner rounds).  Conclusion: ~64-160 blocks with K=256 slices is the
//  sweet spot; inter-kernel boundary is the cheap coherence mechanism.

// ---- K1: encmean[b][e] = (1/S)*sum_s concat(emb_in[src], emb_pos[pos]) ----
__global__ __launch_bounds__(256, 1)
void k1_encmean(const int* __restrict__ src, const int* __restrict__ pos,
                const float* __restrict__ emb_in, const float* __restrict__ emb_pos,
                u16* __restrict__ encmean) {
    int b = blockIdx.x, q4 = blockIdx.y, t = threadIdx.x;
    __shared__ int sidx[S_], pidx[S_];
    __shared__ float part[256][4];
    if (t < S_) { sidx[t] = src[b * S_ + t]; pidx[t] = pos[b * S_ + t]; }
    __syncthreads();

    int f4 = t & 63, g = t >> 6;
    bool isPos = (q4 >= 2);
    const float* base = isPos ? emb_pos : emb_in;
    const int*   idx  = isPos ? pidx : sidx;
    int col = (q4 & 1) * 256 + f4 * 4;          // column within the 512-wide table

    float a0 = 0.f, a1 = 0.f, a2 = 0.f, a3 = 0.f;
    int s0 = g * 25;
    #pragma unroll                               // full: 25 row-loads in flight
    for (int s = s0; s < s0 + 25; s++) {
        const float4 v = *(const float4*)(base + (size_t)idx[s] * E_ + col);
        a0 += v.x; a1 += v.y; a2 += v.z; a3 += v.w;
    }
    part[t][0] = a0; part[t][1] = a1; part[t][2] = a2; part[t][3] = a3;
    __syncthreads();

    if (t < 64) {
        const float inv = 1.0f / (float)S_;
        float r0 = 0.f, r1 = 0.f, r2 = 0.f, r3 = 0.f;
        #pragma unroll
        for (int g2 = 0; g2 < 4; g2++) {
            r0 += part[g2 * 64 + t][0]; r1 += part[g2 * 64 + t][1];
            r2 += part[g2 * 64 + t][2]; r3 += part[g2 * 64 + t][3];
        }
        int e = q4 * 256 + t * 4;
        u16* o = encmean + (size_t)b * (2 * E_) + e;
        o[0] = f2bf(r0 * inv); o[1] = f2bf(r1 * inv);
        o[2] = f2bf(r2 * inv); o[3] = f2bf(r3 * inv);
    }
}

// ---- LDS-staged double-buffered MFMA GEMM over a K-slice -------------------
// acc += A[64 rows, LDA][koff..koff+KLEN] * W[64 rows jt.., LDW][koff..]^T
// LDS layout: row rr (0..63), 16B-unit U (0..15) stored at U ^ (rr & 15).
#define MFMA16(a, bfrag, c) __builtin_amdgcn_mfma_f32_16x16x32_bf16((a), (bfrag), (c), 0, 0, 0)

template<int KLEN, int LDA, int LDW>
__device__ __forceinline__ void gemm_lds(const u16* __restrict__ A,
                                         const float* __restrict__ W,
                                         int jt, int koff, u16* __restrict__ ldsW,
                                         f32x4 acc[4], int t) {
    constexpr int NC = KLEN / Kc;
    const int lane = t & 63, w = t >> 6, m = lane & 15, q = lane >> 4;
    const int r = t >> 2, c4 = t & 3;          // staging: 4 threads per W row
    const float* wsrc = W + (size_t)(jt + r) * LDW + koff + c4 * 4;
    const u16*   arow = A + (size_t)(w * 16 + m) * LDA + koff + q * 8;
    const int halfoff = (c4 & 1) * 4;          // u16 offset within 16B unit

    float4 v[8];
    // ---- prologue: stage chunk 0 into buf 0 ----
    #pragma unroll
    for (int i = 0; i < 8; i++) v[i] = *(const float4*)(wsrc + i * 16);
    #pragma unroll
    for (int i = 0; i < 8; i++) {
        int U = (c4 >> 1) + 2 * i;
        uint2 p; p.x = pack2(v[i].x, v[i].y); p.y = pack2(v[i].z, v[i].w);
        *(uint2*)(ldsW + r * PITCH + ((U ^ (r & 15)) * 8) + halfoff) = p;
    }
    __syncthreads();

    for (int c = 0; c < NC; c++) {
        // issue next chunk's global loads (land while we MFMA)
        if (c + 1 < NC) {
            #pragma unroll
            for (int i = 0; i < 8; i++)
                v[i] = *(const float4*)(wsrc + (c + 1) * Kc + i * 16);
        }
        // compute on buf c&1
        const u16* lb = ldsW + (c & 1) * (64 * PITCH);
        const u16* ar = arow + c * Kc;
        #pragma unroll
        for (int ks = 0; ks < 4; ks++) {
            bf16x8 a = *(const bf16x8*)(ar + ks * 32);
            #pragma unroll
            for (int f = 0; f < 4; f++) {
                int rr = f * 16 + m;
                int U  = ks * 4 + q;
                bf16x8 bfr = *(const bf16x8*)(lb + rr * PITCH + ((U ^ (rr & 15)) * 8));
                acc[f] = MFMA16(a, bfr, acc[f]);
            }
        }
        // write the staged chunk
        if (c + 1 < NC) {
            u16* wd = ldsW + ((c + 1) & 1) * (64 * PITCH) + r * PITCH;
            #pragma unroll
            for (int i = 0; i < 8; i++) {
                int U = (c4 >> 1) + 2 * i;
                uint2 p; p.x = pack2(v[i].x, v[i].y); p.y = pack2(v[i].z, v[i].w);
                *(uint2*)(wd + ((U ^ (r & 15)) * 8) + halfoff) = p;
            }
        }
        __syncthreads();
    }
}

// ---- K2p: part2[sp][b][j] = encmean[b][sp*256..+256] @ Wscale^T slice -----
// grid (16, 4): 64 blocks.
__global__ __launch_bounds__(256, 2)
void k2_h0p(const u16* __restrict__ encmean, const float* __restrict__ Wscale,
            float* __restrict__ part2) {
    __shared__ u16 ldsW[2 * 64 * PITCH];
    int t = threadIdx.x, lane = t & 63, w = t >> 6, m = lane & 15, q = lane >> 4;
    int jt = blockIdx.x * 64, sp = blockIdx.y;
    f32x4 acc[4] = {{0,0,0,0},{0,0,0,0},{0,0,0,0},{0,0,0,0}};
    gemm_lds<256, 2 * E_, 2 * E_>(encmean, Wscale, jt, sp * 256, ldsW, acc, t);
    #pragma unroll
    for (int f = 0; f < 4; f++) {
        int j = jt + 16 * f + m;
        #pragma unroll
        for (int r2 = 0; r2 < 4; r2++) {
            int bb = w * 16 + q * 4 + r2;
            part2[(size_t)(sp * B_ + bb) * H_ + j] = acc[f][r2];
        }
    }
}

// ---- K3: h0 = sum(part2)+bias; energy -> softmax -> context; x; h0b ------
__global__ __launch_bounds__(256, 1)
void k3_attn(const int* __restrict__ src, const int* __restrict__ pos,
             const int* __restrict__ tgt,
             const float* __restrict__ emb_in, const float* __restrict__ emb_pos,
             const float* __restrict__ emb_out,
             const float* __restrict__ part2, const float* __restrict__ bscale,
             u16* __restrict__ x, u16* __restrict__ h0b) {
    int b = blockIdx.x, t = threadIdx.x;       // 256 threads
    __shared__ float h0s[2 * E_];
    __shared__ int sidx[S_], pidx[S_];
    __shared__ float energy[S_];
    __shared__ float align_s[S_];

    for (int i = t; i < 2 * E_; i += 256) {    // reduce K-split partials + bias
        float v = bscale[i];
        #pragma unroll
        for (int ks = 0; ks < NS2; ks++) v += part2[(size_t)(ks * B_ + b) * H_ + i];
        h0s[i] = v;
        h0b[(size_t)b * H_ + i] = f2bf(v);     // bf16 copy for K4's Whh GEMM
    }
    if (t < S_) { sidx[t] = src[b * S_ + t]; pidx[t] = pos[b * S_ + t]; }
    __syncthreads();

    int lane = t & 63, w = t >> 6;
    for (int s = w; s < S_; s += 4) {
        const float* ri = emb_in  + (size_t)sidx[s] * E_;
        const float* rp = emb_pos + (size_t)pidx[s] * E_;
        float acc = 0.f;
        #pragma unroll
        for (int ii = 0; ii < 8; ii++) { int k = lane + 64 * ii; acc += ri[k] * h0s[k]; }
        #pragma unroll
        for (int ii = 0; ii < 8; ii++) { int k = lane + 64 * ii; acc += rp[k] * h0s[E_ + k]; }
        #pragma unroll
        for (int off = 32; off; off >>= 1) acc += __shfl_down(acc, off);
        if (lane == 0) energy[s] = acc;
    }
    __syncthreads();

    if (t < 64) {
        float e0 = energy[t];
        float e1 = (t + 64 < S_) ? energy[t + 64] : -1e30f;
        float mx = fmaxf(e0, e1);
        #pragma unroll
        for (int off = 32; off; off >>= 1) mx = fmaxf(mx, __shfl_xor(mx, off));
        float p0 = expf(e0 - mx);
        float p1 = (t + 64 < S_) ? expf(e1 - mx) : 0.f;
        float ss = p0 + p1;
        #pragma unroll
        for (int off = 32; off; off >>= 1) ss += __shfl_xor(ss, off);
        float inv = 1.0f / (ss * (float)S_);   // fold torch.mean's 1/S here
        align_s[t] = p0 * inv;
        if (t + 64 < S_) align_s[t + 64] = p1 * inv;
    }
    __syncthreads();

    if (t < 128) {
        int o = t;
        bool isPos = (o >= 64);
        const float* base = isPos ? emb_pos : emb_in;
        const int* idx  = isPos ? pidx : sidx;
        int eo = (o & 63) * 8;
        float c[8] = {0,0,0,0,0,0,0,0};
        #pragma unroll 4                        // 8 L2-warm loads in flight
        for (int s = 0; s < S_; s++) {
            const float* row = base + (size_t)idx[s] * E_ + eo;
            float al = align_s[s];
            const float4 v0 = *(const float4*)(row);
            const float4 v1 = *(const float4*)(row + 4);
            c[0] += al * v0.x; c[1] += al * v0.y; c[2] += al * v0.z; c[3] += al * v0.w;
            c[4] += al * v1.x; c[5] += al * v1.y; c[6] += al * v1.z; c[7] += al * v1.w;
        }
        u16* xo = x + (size_t)b * (E_ + H_) + E_ + o * 8;
        #pragma unroll
        for (int i = 0; i < 8; i++) xo[i] = f2bf(c[i]);
    } else {
        int i = t - 128;                        // 128 threads x 4 elems = 512
        int tw = tgt[b];
        const float4 v = *((const float4*)(emb_out + (size_t)tw * E_) + i);
        ushort4 o; o.x = f2bf(v.x); o.y = f2bf(v.y); o.z = f2bf(v.z); o.w = f2bf(v.w);
        *((ushort4*)(x + (size_t)b * (E_ + H_)) + i) = o;
    }
}

// ---- K4p: partial z slices. grid (16, 10): sp<6 -> x@Wih; sp>=6 -> h0@Whh -
__global__ __launch_bounds__(256, 2)
void k4_hp(const u16* __restrict__ xb, const float* __restrict__ Wih,
           const u16* __restrict__ h0b, const float* __restrict__ Whh,
           float* __restrict__ part4) {
    __shared__ u16 ldsW[2 * 64 * PITCH];
    int t = threadIdx.x, lane = t & 63, w = t >> 6, m = lane & 15, q = lane >> 4;
    int jt = blockIdx.x * 64, sp = blockIdx.y;
    f32x4 acc[4] = {{0,0,0,0},{0,0,0,0},{0,0,0,0},{0,0,0,0}};
    if (sp < 6) gemm_lds<256, E_ + H_, E_ + H_>(xb,  Wih, jt, sp * 256,       ldsW, acc, t);
    else        gemm_lds<256, H_,      H_     >(h0b, Whh, jt, (sp - 6) * 256, ldsW, acc, t);
    #pragma unroll
    for (int f = 0; f < 4; f++) {
        int j = jt + 16 * f + m;
        #pragma unroll
        for (int r2 = 0; r2 < 4; r2++) {
            int bb = w * 16 + q * 4 + r2;
            part4[(size_t)(sp * B_ + bb) * H_ + j] = acc[f][r2];
        }
    }
}

// ---- K4r: h = tanh(sum(part4) + bih + bhh); f32 out + bf16 copy -----------
__global__ __launch_bounds__(256, 1)
void k4_red(const float* __restrict__ part4,
            const float* __restrict__ bih, const float* __restrict__ bhh,
            float* __restrict__ houtf, u16* __restrict__ hbf) {
    int b = blockIdx.x, t = threadIdx.x;
    int j = t * 4;
    float4 s  = *(const float4*)(bih + j);
    const float4 b2 = *(const float4*)(bhh + j);
    s.x += b2.x; s.y += b2.y; s.z += b2.z; s.w += b2.w;
    #pragma unroll
    for (int ks = 0; ks < NS4; ks++) {
        const float4 p = *(const float4*)(part4 + (size_t)(ks * B_ + b) * H_ + j);
        s.x += p.x; s.y += p.y; s.z += p.z; s.w += p.w;
    }
    float4 h; h.x = tanhf(s.x); h.y = tanhf(s.y); h.z = tanhf(s.z); h.w = tanhf(s.w);
    *(float4*)(houtf + (size_t)b * H_ + j) = h;
    ushort4 o; o.x = f2bf(h.x); o.y = f2bf(h.y); o.z = f2bf(h.z); o.w = f2bf(h.w);
    *(ushort4*)(hbf + (size_t)b * H_ + j) = o;
}

// ---- K5: out = h @ W_proj^T + b_proj  (131 MB f32 weights, HBM-bound) -----
__global__ __launch_bounds__(256, 2)
void k5_out(const u16* __restrict__ hb, const float* __restrict__ Wp,
            const float* __restrict__ bp, float* __restrict__ out) {
    __shared__ u16 ldsW[2 * 64 * PITCH];
    int t = threadIdx.x, lane = t & 63, w = t >> 6, m = lane & 15, q = lane >> 4;
    int jt = blockIdx.x * 64;
    f32x4 acc[4] = {{0,0,0,0},{0,0,0,0},{0,0,0,0},{0,0,0,0}};
    gemm_lds<H_, H_, H_>(hb, Wp, jt, 0, ldsW, acc, t);
    #pragma unroll
    for (int f = 0; f < 4; f++) {
        int j = jt + 16 * f + m;
        float bias = bp[j];
        #pragma unroll
        for (int r = 0; r < 4; r++) {
            int b = w * 16 + q * 4 + r;
            out[(size_t)b * VT_ + j] = acc[f][r] + bias;
        }
    }
}

// ---- launch ---------------------------------------------------------------
extern "C" void kernel_launch(void* const* d_in, const int* in_sizes, int n_in,
                              void* d_out, int out_size, void* d_ws, size_t ws_size,
                              hipStream_t stream) {
    const int*   src     = (const int*)d_in[0];
    const int*   pos     = (const int*)d_in[1];
    const int*   tgt     = (const int*)d_in[2];
    const float* emb_in  = (const float*)d_in[5];
    const float* emb_out = (const float*)d_in[6];
    const float* emb_pos = (const float*)d_in[7];
    const float* Wscale  = (const float*)d_in[8];
    const float* bscale  = (const float*)d_in[9];
    const float* Wih     = (const float*)d_in[10];
    const float* bih     = (const float*)d_in[11];
    const float* Whh     = (const float*)d_in[12];
    const float* bhh     = (const float*)d_in[13];
    const float* Wproj   = (const float*)d_in[14];
    const float* bproj   = (const float*)d_in[15];

    char* ws = (char*)d_ws;
    u16*   encmean = (u16*)(ws);                 // 64*1024*2      = 131072 B
    u16*   xb      = (u16*)(ws + 131072);        // 64*1536*2      = 196608 B
    u16*   h0b     = (u16*)(ws + 327680);        // 64*1024*2      = 131072 B
    u16*   hbf     = (u16*)(ws + 458752);        // 64*1024*2      = 131072 B
    float* part2   = (float*)(ws + 589824);      // 4*64*1024*4    = 1048576 B
    float* part4   = (float*)(ws + 1638400);     // 10*64*1024*4   = 2621440 B
                                                 // total ~4.26 MB

    float* out   = (float*)d_out;                // [64][32000] f32
    float* houtf = out + (size_t)B_ * VT_;       // [64][1024]  f32 (Output 1)

    hipLaunchKernelGGL(k1_encmean, dim3(B_, 4),        dim3(256), 0, stream,
                       src, pos, emb_in, emb_pos, encmean);
    hipLaunchKernelGGL(k2_h0p,     dim3(H_ / 64, NS2), dim3(256), 0, stream,
                       encmean, Wscale, part2);
    hipLaunchKernelGGL(k3_attn,    dim3(B_),           dim3(256), 0, stream,
                       src, pos, tgt, emb_in, emb_pos, emb_out, part2, bscale,
                       xb, h0b);
    hipLaunchKernelGGL(k4_hp,      dim3(H_ / 64, NS4), dim3(256), 0, stream,
                       xb, Wih, h0b, Whh, part4);
    hipLaunchKernelGGL(k4_red,     dim3(B_),           dim3(256), 0, stream,
                       part4, bih, bhh, houtf, hbf);
    hipLaunchKernelGGL(k5_out,     dim3(VT_ / 64),     dim3(256), 0, stream,
                       hbf, Wproj, bproj, out);
}